// Round 14
// baseline (1006.906 us; speedup 1.0000x reference)
//
#include <hip/hip_runtime.h>
#include <hip/hip_bf16.h>

#define INF_F 1000000000000.0f

typedef __attribute__((ext_vector_type(8))) short bfrag8;
typedef __attribute__((ext_vector_type(4))) float facc4;
typedef __attribute__((ext_vector_type(4))) short short4v;

__device__ __forceinline__ float sigf(float x){ return 1.0f/(1.0f + expf(-x)); }
__device__ __forceinline__ short f2bf(float f){
  __hip_bfloat16 h = __float2bfloat16(f);
  return *reinterpret_cast<short*>(&h);
}
__device__ __forceinline__ float bf2f(short s){
  unsigned u = ((unsigned)(unsigned short)s) << 16;
  return *reinterpret_cast<float*>(&u);
}

// out-region offsets (floats)
#define OFF_LOG 0ull
#define OFF_A   32819200ull
#define OFF_C   33228800ull
#define OFF_E   33638400ull

// ---------------- init ----------------
__global__ __launch_bounds__(256) void k_init(const float* __restrict__ init_s,
    float* __restrict__ hbuf, float* __restrict__ c0, float* __restrict__ ctxb,
    float* __restrict__ cov) {
  int i = blockIdx.x*256 + threadIdx.x;
  if (i < 32*512) { float v = init_s[i]; hbuf[i]=v; c0[i]=v; ctxb[i]=0.0f; }
  if (i < 32*400) cov[i] = 0.0f;
}

// ---------------- b_combo = W_ih@b_red + b_ih + b_hh ----------------
__global__ __launch_bounds__(256) void k_bcombo(const float* __restrict__ W_ih,
    const float* __restrict__ b_red, const float* __restrict__ b_ih,
    const float* __restrict__ b_hh, float* __restrict__ bcomb) {
  int j = blockIdx.x*256 + threadIdx.x;
  if (j >= 2048) return;
  float acc = b_ih[j] + b_hh[j];
  for (int m=0;m<300;m++) acc += W_ih[j*300+m]*b_red[m];
  bcomb[j] = acc;
}

// ---------------- Wct[2048][812] = W_ih[2048x300] @ W_red[300x812] ----------------
__global__ __launch_bounds__(256) void k_wcombo(const float* __restrict__ W_ih,
    const float* __restrict__ W_red, float* __restrict__ Wct) {
  __shared__ float As[16][68];
  __shared__ float Bs[16][68];
  int tid = threadIdx.x;
  int m0 = blockIdx.y*64, n0 = blockIdx.x*64;
  int rl = tid>>2, kq = (tid&3)*4;
  int kl = tid>>4, c4 = (tid&15)*4;
  int tx = tid&15, ty = tid>>4;
  float acc[4][4]={};
  for (int kk=0;kk<300;kk+=16){
    #pragma unroll
    for (int q=0;q<4;q++){
      int kg = kk+kq+q;
      As[kq+q][rl] = (kg<300) ? W_ih[(size_t)(m0+rl)*300 + kg] : 0.0f;
    }
    #pragma unroll
    for (int q=0;q<4;q++){
      int c = n0 + c4 + q;
      Bs[kl][c4+q] = (kk+kl<300 && c<812) ? W_red[(size_t)(kk+kl)*812 + c] : 0.0f;
    }
    __syncthreads();
    #pragma unroll
    for (int k=0;k<16;k++){
      const float* ap=&As[k][ty*4]; const float* bp=&Bs[k][tx*4];
      #pragma unroll
      for (int i=0;i<4;i++)
        #pragma unroll
        for (int j=0;j<4;j++) acc[i][j] += ap[i]*bp[j];
    }
    __syncthreads();
  }
  #pragma unroll
  for (int i=0;i<4;i++)
    #pragma unroll
    for (int j=0;j<4;j++){
      int row = m0+ty*4+i, col = n0+tx*4+j;
      if (col<812) Wct[(size_t)row*812 + col] = acc[i][j];
    }
}

// ---------------- G_emb[1024][2048] = emb[1024x300] @ Wct[:,0:300]^T + b_combo --------
__global__ __launch_bounds__(256) void k_gemb(const float* __restrict__ trg,
    const float* __restrict__ Wct, const float* __restrict__ bcomb,
    float* __restrict__ Gemb) {
  __shared__ float As[16][68];
  __shared__ float Bs[16][68];
  int tid = threadIdx.x;
  int m0 = blockIdx.y*64, n0 = blockIdx.x*64;
  int rl = tid>>2, kq = (tid&3)*4;
  int tx = tid&15, ty = tid>>4;
  float acc[4][4]={};
  int r = m0 + rl;
  const float* arow = trg + (size_t)(r&31)*9600 + (size_t)(r>>5)*300;
  for (int kk=0;kk<300;kk+=16){
    #pragma unroll
    for (int q=0;q<4;q++){
      int kg = kk+kq+q;
      As[kq+q][rl] = (kg<300) ? arow[kg] : 0.0f;
      Bs[kq+q][rl] = (kg<300) ? Wct[(size_t)(n0+rl)*812 + kg] : 0.0f;
    }
    __syncthreads();
    #pragma unroll
    for (int k=0;k<16;k++){
      const float* ap=&As[k][ty*4]; const float* bp=&Bs[k][tx*4];
      #pragma unroll
      for (int i=0;i<4;i++)
        #pragma unroll
        for (int j=0;j<4;j++) acc[i][j] += ap[i]*bp[j];
    }
    __syncthreads();
  }
  #pragma unroll
  for (int i=0;i<4;i++)
    #pragma unroll
    for (int j=0;j<4;j++){
      int rr = m0+ty*4+i, col = n0+tx*4+j;
      Gemb[(size_t)rr*2048 + col] = acc[i][j] + bcomb[col];
    }
}

// ---------------- fused prep: Wg pack + enc/W_enc hi-lo split + W_log/W_cat conv -----
// block sections: [0,8192) wgpack; [8192,14848) convsplit; [14848,31360) wlogconv
__global__ __launch_bounds__(256) void k_prep(const float* __restrict__ Wct,
    const float* __restrict__ W_hh, float* __restrict__ Wg,
    const float* __restrict__ enc, const float* __restrict__ W_enc,
    short* __restrict__ ehi, short* __restrict__ elo,
    short* __restrict__ whi, short* __restrict__ wlo,
    const float* __restrict__ W_log, __hip_bfloat16* __restrict__ wlb,
    const float* __restrict__ W_cat, short* __restrict__ wcatb) {
  int bx = blockIdx.x;
  if (bx < 8192) {
    int idx = bx*256 + threadIdx.x;
    int k = idx >> 11, j = idx & 2047;
    Wg[idx] = (k < 512) ? Wct[(size_t)j*812 + 300 + k] : W_hh[(size_t)j*512 + (k-512)];
  } else if (bx < 14848) {
    int i4 = (bx-8192)*256 + threadIdx.x;
    const float* src; short* dhi; short* dlo; size_t off;
    if (i4 < 1638400) { src = enc;   dhi = ehi; dlo = elo; off = (size_t)i4*4; }
    else { int j4 = i4 - 1638400; if (j4 >= 65536) return;
           src = W_enc; dhi = whi; dlo = wlo; off = (size_t)j4*4; }
    float4 v = *(const float4*)(src + off);
    float f[4] = {v.x, v.y, v.z, v.w};
    short4v h, l;
    #pragma unroll
    for (int q=0;q<4;q++){
      short hb = f2bf(f[q]);
      float rr = f[q] - bf2f(hb);
      h[q] = hb; l[q] = f2bf(rr);
    }
    *(short4v*)(dhi + off) = h;
    *(short4v*)(dlo + off) = l;
  } else {
    int i4 = (bx-14848)*256 + threadIdx.x;
    if (i4 < 4096000) {
      const float4 v = *(const float4*)(W_log + (size_t)i4*4);
      size_t o = (size_t)i4*4;
      wlb[o+0] = __float2bfloat16(v.x); wlb[o+1] = __float2bfloat16(v.y);
      wlb[o+2] = __float2bfloat16(v.z); wlb[o+3] = __float2bfloat16(v.w);
    } else {
      int j4 = i4 - 4096000;
      if (j4 >= 131072) return;
      const float4 v = *(const float4*)(W_cat + (size_t)j4*4);
      short4v s;
      s[0]=f2bf(v.x); s[1]=f2bf(v.y); s[2]=f2bf(v.z); s[3]=f2bf(v.w);
      *(short4v*)(wcatb + (size_t)j4*4) = s;
    }
  }
}

// swizzled LDS byte offset: row in [0,128), slot in [0,4) (16B granules of a 64B row)
__device__ __forceinline__ int lds_off(int row, int slot) {
  return (row<<6) + (((slot ^ ((row>>1)&3))&3)<<4);
}

// ---------------- memories = enc @ W_enc^T + b_enc  (split-precision 3xbf16 MFMA) ----
__global__ __launch_bounds__(256) void k_memories(const short* __restrict__ Ahg,
    const short* __restrict__ Alg, const short* __restrict__ Bhg,
    const short* __restrict__ Blg, const float* __restrict__ bias,
    float* __restrict__ mem) {
  __shared__ short Ah[4096];
  __shared__ short Al[4096];
  __shared__ short Bh[4096];
  __shared__ short Bl[4096];
  int tid = threadIdx.x;
  int m0 = blockIdx.x*128, n0 = blockIdx.y*128;
  int w = tid>>6, lane = tid&63;
  int wr = w>>1, wc = w&1;
  int lr = lane&15, kg2 = lane>>4;

  int srow = tid>>1;
  int ss   = (tid&1)*2;
  const short* gah = Ahg + (size_t)(m0+srow)*512 + ss*8;
  const short* gal = Alg + (size_t)(m0+srow)*512 + ss*8;
  const short* gbh = Bhg + (size_t)(n0+srow)*512 + ss*8;
  const short* gbl = Blg + (size_t)(n0+srow)*512 + ss*8;
  int wo0 = lds_off(srow, ss), wo1 = lds_off(srow, ss+1);

  int raoff[4], rboff[4];
  #pragma unroll
  for (int q=0;q<4;q++){
    raoff[q] = lds_off(wr*64 + q*16 + lr, kg2);
    rboff[q] = lds_off(wc*64 + q*16 + lr, kg2);
  }

  facc4 acc[4][4] = {};
  bfrag8 rah0 = *(const bfrag8*)(gah);
  bfrag8 rah1 = *(const bfrag8*)(gah+8);
  bfrag8 ral0 = *(const bfrag8*)(gal);
  bfrag8 ral1 = *(const bfrag8*)(gal+8);
  bfrag8 rbh0 = *(const bfrag8*)(gbh);
  bfrag8 rbh1 = *(const bfrag8*)(gbh+8);
  bfrag8 rbl0 = *(const bfrag8*)(gbl);
  bfrag8 rbl1 = *(const bfrag8*)(gbl+8);

  for (int i=0;i<16;i++){
    __syncthreads();
    *(bfrag8*)((char*)Ah + wo0) = rah0;
    *(bfrag8*)((char*)Ah + wo1) = rah1;
    *(bfrag8*)((char*)Al + wo0) = ral0;
    *(bfrag8*)((char*)Al + wo1) = ral1;
    *(bfrag8*)((char*)Bh + wo0) = rbh0;
    *(bfrag8*)((char*)Bh + wo1) = rbh1;
    *(bfrag8*)((char*)Bl + wo0) = rbl0;
    *(bfrag8*)((char*)Bl + wo1) = rbl1;
    __syncthreads();
    if (i<15){
      gah += 32; gal += 32; gbh += 32; gbl += 32;
      rah0 = *(const bfrag8*)(gah);
      rah1 = *(const bfrag8*)(gah+8);
      ral0 = *(const bfrag8*)(gal);
      ral1 = *(const bfrag8*)(gal+8);
      rbh0 = *(const bfrag8*)(gbh);
      rbh1 = *(const bfrag8*)(gbh+8);
      rbl0 = *(const bfrag8*)(gbl);
      rbl1 = *(const bfrag8*)(gbl+8);
    }
    bfrag8 afh[4], afl[4], bfh[4], bfl[4];
    #pragma unroll
    for (int q=0;q<4;q++){
      afh[q] = *(const bfrag8*)((char*)Ah + raoff[q]);
      afl[q] = *(const bfrag8*)((char*)Al + raoff[q]);
      bfh[q] = *(const bfrag8*)((char*)Bh + rboff[q]);
      bfl[q] = *(const bfrag8*)((char*)Bl + rboff[q]);
    }
    #pragma unroll
    for (int mi=0;mi<4;mi++)
      #pragma unroll
      for (int ni=0;ni<4;ni++){
        acc[mi][ni] = __builtin_amdgcn_mfma_f32_16x16x32_bf16(afl[mi], bfh[ni], acc[mi][ni], 0,0,0);
        acc[mi][ni] = __builtin_amdgcn_mfma_f32_16x16x32_bf16(afh[mi], bfl[ni], acc[mi][ni], 0,0,0);
        acc[mi][ni] = __builtin_amdgcn_mfma_f32_16x16x32_bf16(afh[mi], bfh[ni], acc[mi][ni], 0,0,0);
      }
  }

  #pragma unroll
  for (int mi=0;mi<4;mi++){
    int row = m0 + wr*64 + mi*16 + kg2*4;
    #pragma unroll
    for (int ni=0;ni<4;ni++){
      int col = n0 + wc*64 + ni*16 + lr;
      float bl = bias[col];
      #pragma unroll
      for (int q=0;q<4;q++)
        mem[(size_t)(row+q)*512 + col] = acc[mi][ni][q] + bl;
    }
  }
}

// ---------------- per-step: gates partial GEMM (8 k-slices of 128, 512 threads) ------
// grid (ks=8, rc=32); partial[ks*32+b][row] = sum_{k in slice} yh[b][k]*Wg[k][row]
__global__ __launch_bounds__(512) void k_gates(const float* __restrict__ ctxb,
    const float* __restrict__ hbuf, const float* __restrict__ Wg,
    float* __restrict__ partials) {
  __shared__ float yh_s[128][32];
  int ks = blockIdx.x;
  int rc = blockIdx.y;
  int tid = threadIdx.x;
  const float* side = (ks < 4) ? ctxb : hbuf;
  int kbase = (ks & 3) * 128;
  {
    int b_l = tid >> 4, kq0 = (tid & 15) * 8;
    const float* src = side + (size_t)b_l*512 + kbase + kq0;
    float4 v0 = *(const float4*)(src);
    float4 v1 = *(const float4*)(src + 4);
    yh_s[kq0+0][b_l]=v0.x; yh_s[kq0+1][b_l]=v0.y;
    yh_s[kq0+2][b_l]=v0.z; yh_s[kq0+3][b_l]=v0.w;
    yh_s[kq0+4][b_l]=v1.x; yh_s[kq0+5][b_l]=v1.y;
    yh_s[kq0+6][b_l]=v1.z; yh_s[kq0+7][b_l]=v1.w;
  }
  __syncthreads();
  int tr = tid & 63, bg = tid >> 6;   // row-lane(64), b-group (wave-uniform)
  int row = rc*64 + tr;
  float acc[4] = {};
  const float* wp = Wg + (size_t)(ks*128)*2048 + row;
  #pragma unroll 8
  for (int k=0;k<128;k++){
    float w = wp[(size_t)k*2048];
    float4 y = *(const float4*)&yh_s[k][bg*4];
    acc[0]+=w*y.x; acc[1]+=w*y.y; acc[2]+=w*y.z; acc[3]+=w*y.w;
  }
  #pragma unroll
  for (int j=0;j<4;j++)
    partials[(size_t)(ks*32 + bg*4 + j)*2048 + row] = acc[j];
}

// ---------------- per-step: partial reduce (8) + LSTM + energy chunk (512 thr) -------
// grid 256 linear blocks: b = blk&31, sc = blk>>5
__global__ __launch_bounds__(512) void k_lstm_energy(const float* __restrict__ part,
    const float* __restrict__ Gemb,
    const float* __restrict__ c_in, float* __restrict__ c_out,
    float* __restrict__ hbuf, short* __restrict__ licat,
    const float* __restrict__ mem, const int* __restrict__ emask,
    float* __restrict__ out, int t) {
  __shared__ float hl[512];
  int blk = blockIdx.x, tid = threadIdx.x;
  int b = blk & 31, sc = blk >> 5;
  int r = t*32 + b;
  int lane = tid & 63, w = tid >> 6;   // 8 waves
  {
    int j = tid;
    const float* gp = Gemb + (size_t)r*2048;
    float g[4];
    #pragma unroll
    for (int gi=0; gi<4; gi++){
      int row = gi*512 + j;
      float v = gp[row];
      #pragma unroll
      for (int ks=0; ks<8; ks++)
        v += part[(size_t)(ks*32+b)*2048 + row];
      g[gi] = v;
    }
    float cp = c_in[b*512+j];
    float cn = sigf(g[1])*cp + sigf(g[0])*tanhf(g[2]);
    float hn = sigf(g[3])*tanhf(cn);
    hl[j] = hn;
    if (sc==0){
      c_out[b*512+j]=cn; hbuf[b*512+j]=hn;
      licat[(size_t)r*1024 + j] = f2bf(hn);
    }
  }
  __syncthreads();
  float4 h0 = *(const float4*)&hl[lane*8];
  float4 h1 = *(const float4*)&hl[lane*8+4];
  const float* mb = mem + (size_t)b*204800;
  const int* em = emask + b*400;
  for (int i=0;i<7;i++){
    int s_l = i*8 + w;
    if (s_l < 50){
      int s = sc*50 + s_l;
      const float4* mp = (const float4*)(mb + (size_t)s*512 + lane*8);
      float4 m0 = mp[0], m1 = mp[1];
      float acc = h0.x*m0.x + h0.y*m0.y + h0.z*m0.z + h0.w*m0.w
                + h1.x*m1.x + h1.y*m1.y + h1.z*m1.z + h1.w*m1.w;
      #pragma unroll
      for (int off=32; off; off>>=1) acc += __shfl_xor(acc, off);
      if (lane==0){
        out[OFF_E + (size_t)r*400 + s] = (em[s]==0) ? -INF_F : acc;
      }
    }
  }
}

// ---------------- per-step: softmax + ctx chunk (64 h, 8 s-eighths) + attn/cov -------
// grid 256 linear blocks: b = blk&31, hc = blk>>5 (8 chunks x 64 h), 512 threads
__global__ __launch_bounds__(512) void k_ctx(float* __restrict__ out,
    const float* __restrict__ mem, float* __restrict__ ctxb, short* __restrict__ licat,
    float* __restrict__ cov, int t) {
  __shared__ float ps[400];
  __shared__ float red[16];
  __shared__ float tmp[512];
  int blk = blockIdx.x, tid = threadIdx.x;
  int b = blk & 31, hc = blk >> 5;
  int r = t*32 + b;
  int lane = tid & 63, w = tid >> 6;   // 8 waves
  float e = (tid < 400) ? out[OFF_E + (size_t)r*400 + tid] : -3.4e38f;
  float lm = e;
  #pragma unroll
  for (int off=32; off; off>>=1) lm = fmaxf(lm, __shfl_xor(lm, off));
  if (lane==0) red[w] = lm;
  __syncthreads();
  float m = red[0];
  #pragma unroll
  for (int i=1;i<8;i++) m = fmaxf(m, red[i]);
  float pv = (tid < 400) ? expf(e - m) : 0.0f;
  float sv = pv;
  #pragma unroll
  for (int off=32; off; off>>=1) sv += __shfl_xor(sv, off);
  if (lane==0) red[8+w] = sv;
  __syncthreads();
  float sum = red[8];
  #pragma unroll
  for (int i=1;i<8;i++) sum += red[8+i];
  float inv = 1.0f/sum;
  if (tid < 400) ps[tid] = pv*inv;
  __syncthreads();
  // ctx chunk: 64 h, eight s-eighths of 50
  int hloc = tid & 63, sh = tid >> 6;
  int h = hc*64 + hloc;
  float acc = 0.0f;
  {
    const float* mqs = mem + (size_t)b*204800 + h + (size_t)sh*50*512;
    const float* pss = &ps[sh*50];
    #pragma unroll 10
    for (int s=0;s<50;s++) acc += pss[s]*mqs[(size_t)s*512];
  }
  tmp[sh*64 + hloc] = acc;
  __syncthreads();
  if (sh==0){
    float v = acc;
    #pragma unroll
    for (int q=1;q<8;q++) v += tmp[q*64 + hloc];
    ctxb[b*512+h] = v;
    licat[(size_t)r*1024 + 512 + h] = f2bf(v);
  }
  if (hc==0 && tid<400){
    float a = ps[tid];
    out[OFF_A + (size_t)r*400 + tid] = a;
    float cv = cov[b*400+tid];
    out[OFF_C + (size_t)r*400 + tid] = cv;
    cov[b*400+tid] = cv + a;
  }
}

// ---------------- logit_in = tanh(licat @ wcatb^T + b_cat) -> bf16 (MFMA, prefetch) --
__global__ __launch_bounds__(256) void k_logitin(const short* __restrict__ Ab,
    const short* __restrict__ Wb, const float* __restrict__ b_cat,
    __hip_bfloat16* __restrict__ lib) {
  __shared__ short As[4096];
  __shared__ short Bs[4096];
  int tid = threadIdx.x;
  int m0 = blockIdx.x*128, n0 = blockIdx.y*128;
  int w = tid>>6, lane = tid&63;
  int wr = w>>1, wc = w&1;
  int lr = lane&15, kg2 = lane>>4;

  int srow = tid>>1;
  int ss   = (tid&1)*2;
  const short* ga = Ab + (size_t)(m0+srow)*1024 + ss*8;
  const short* gw = Wb + (size_t)(n0+srow)*1024 + ss*8;
  int wo0 = lds_off(srow, ss), wo1 = lds_off(srow, ss+1);

  int raoff[4], rboff[4];
  #pragma unroll
  for (int q=0;q<4;q++){
    raoff[q] = lds_off(wr*64 + q*16 + lr, kg2);
    rboff[q] = lds_off(wc*64 + q*16 + lr, kg2);
  }

  facc4 acc[4][4] = {};
  bfrag8 ra0 = *(const bfrag8*)(ga);
  bfrag8 ra1 = *(const bfrag8*)(ga+8);
  bfrag8 rb0 = *(const bfrag8*)(gw);
  bfrag8 rb1 = *(const bfrag8*)(gw+8);

  for (int i=0;i<32;i++){
    __syncthreads();
    *(bfrag8*)((char*)As + wo0) = ra0;
    *(bfrag8*)((char*)As + wo1) = ra1;
    *(bfrag8*)((char*)Bs + wo0) = rb0;
    *(bfrag8*)((char*)Bs + wo1) = rb1;
    __syncthreads();
    if (i<31){
      ga += 32; gw += 32;
      ra0 = *(const bfrag8*)(ga);
      ra1 = *(const bfrag8*)(ga+8);
      rb0 = *(const bfrag8*)(gw);
      rb1 = *(const bfrag8*)(gw+8);
    }
    bfrag8 af[4], bf[4];
    #pragma unroll
    for (int q=0;q<4;q++){
      af[q] = *(const bfrag8*)((char*)As + raoff[q]);
      bf[q] = *(const bfrag8*)((char*)Bs + rboff[q]);
    }
    #pragma unroll
    for (int mi=0;mi<4;mi++)
      #pragma unroll
      for (int ni=0;ni<4;ni++)
        acc[mi][ni] = __builtin_amdgcn_mfma_f32_16x16x32_bf16(af[mi], bf[ni], acc[mi][ni], 0,0,0);
  }

  #pragma unroll
  for (int mi=0;mi<4;mi++){
    int row = m0 + wr*64 + mi*16 + kg2*4;
    #pragma unroll
    for (int ni=0;ni<4;ni++){
      int col = n0 + wc*64 + ni*16 + lr;
      float bc = b_cat[col];
      #pragma unroll
      for (int q=0;q<4;q++){
        float v = tanhf(acc[mi][ni][q] + bc);
        lib[(size_t)(row+q)*512 + col] = __float2bfloat16(v);
      }
    }
  }
}

// ---------------- logits = logit_in @ W_log^T + b_log (bf16 MFMA, XCD swizzle) ------
__global__ __launch_bounds__(256) void k_logits(const __hip_bfloat16* __restrict__ Ab,
    const __hip_bfloat16* __restrict__ Wb, const float* __restrict__ b_log,
    float* __restrict__ out) {
  __shared__ short As[4096];
  __shared__ short Bs[4096];
  int m = blockIdx.y & 7;
  int yy = blockIdx.x + 8*(blockIdx.y >> 3);
  if (yy >= 250) return;
  int tid = threadIdx.x;
  int m0 = m*128, n0 = yy*128;
  int w = tid>>6, lane = tid&63;
  int wr = w>>1, wc = w&1;
  int lr = lane&15, kg2 = lane>>4;
  const short* A = (const short*)Ab;
  const short* W = (const short*)Wb;

  int srow = tid>>1;
  int ss   = (tid&1)*2;
  const short* ga = A + (size_t)(m0+srow)*512 + ss*8;
  const short* gw = W + (size_t)(n0+srow)*512 + ss*8;
  int wo0 = lds_off(srow, ss), wo1 = lds_off(srow, ss+1);

  int raoff[4], rboff[4];
  #pragma unroll
  for (int q=0;q<4;q++){
    raoff[q] = lds_off(wr*64 + q*16 + lr, kg2);
    rboff[q] = lds_off(wc*64 + q*16 + lr, kg2);
  }

  facc4 acc[4][4] = {};
  bfrag8 ra0 = *(const bfrag8*)(ga);
  bfrag8 ra1 = *(const bfrag8*)(ga+8);
  bfrag8 rb0 = *(const bfrag8*)(gw);
  bfrag8 rb1 = *(const bfrag8*)(gw+8);

  for (int i=0;i<16;i++){
    __syncthreads();
    *(bfrag8*)((char*)As + wo0) = ra0;
    *(bfrag8*)((char*)As + wo1) = ra1;
    *(bfrag8*)((char*)Bs + wo0) = rb0;
    *(bfrag8*)((char*)Bs + wo1) = rb1;
    __syncthreads();
    if (i<15){
      ga += 32; gw += 32;
      ra0 = *(const bfrag8*)(ga);
      ra1 = *(const bfrag8*)(ga+8);
      rb0 = *(const bfrag8*)(gw);
      rb1 = *(const bfrag8*)(gw+8);
    }
    bfrag8 af[4], bf[4];
    #pragma unroll
    for (int q=0;q<4;q++){
      af[q] = *(const bfrag8*)((char*)As + raoff[q]);
      bf[q] = *(const bfrag8*)((char*)Bs + rboff[q]);
    }
    #pragma unroll
    for (int mi=0;mi<4;mi++)
      #pragma unroll
      for (int ni=0;ni<4;ni++)
        acc[mi][ni] = __builtin_amdgcn_mfma_f32_16x16x32_bf16(af[mi], bf[ni], acc[mi][ni], 0,0,0);
  }

  #pragma unroll
  for (int mi=0;mi<4;mi++){
    int row = m0 + wr*64 + mi*16 + kg2*4;
    #pragma unroll
    for (int ni=0;ni<4;ni++){
      int col = n0 + wc*64 + ni*16 + lr;
      float bl = b_log[col];
      #pragma unroll
      for (int q=0;q<4;q++){
        float v = acc[mi][ni][q] + bl;
        out[(size_t)(row+q)*32050 + col] = (v == 0.0f) ? -INF_F : v;
      }
    }
  }
}

// ---------------- scatter-max of energies into extended logits (+ OOV fill) ---------
__global__ __launch_bounds__(512) void k_scatter(const int* __restrict__ ext_src,
    float* __restrict__ out) {
  __shared__ int tok[400];
  __shared__ float ev[400];
  int rr = blockIdx.x;
  int b = rr & 31;
  int tid = threadIdx.x;
  if (tid >= 400 && tid < 450)
    out[(size_t)rr*32050 + 32000 + (tid-400)] = -INF_F;
  if (tid < 400){
    tok[tid] = ext_src[b*400+tid];
    ev[tid]  = out[OFF_E + (size_t)rr*400 + tid];
  }
  __syncthreads();
  if (tid < 400){
    int tk = tok[tid];
    float m = -3.4e38f;
    bool pre = false;
    #pragma unroll 1
    for (int s2=0; s2<400; s2+=8){
      #pragma unroll
      for (int q=0;q<8;q++){
        int tk2 = tok[s2+q];
        float e2 = ev[s2+q];
        bool eq = (tk2==tk);
        m = fmaxf(m, eq ? e2 : -3.4e38f);
        pre = pre || (eq && (s2+q) < tid);
      }
    }
    if (!pre && m != -INF_F){
      size_t idx = (size_t)rr*32050 + tk;
      float wv = out[idx];
      float extv = (wv == -INF_F) ? 0.0f : wv;
      float nv = extv + m;
      out[idx] = (nv == 0.0f) ? -INF_F : nv;
    }
  }
}

extern "C" void kernel_launch(void* const* d_in, const int* in_sizes, int n_in,
                              void* d_out, int out_size, void* d_ws, size_t ws_size,
                              hipStream_t stream) {
  const float* trg   = (const float*)d_in[0];
  const int*   ext   = (const int*)  d_in[1];
  const float* inits = (const float*)d_in[2];
  const float* enc   = (const float*)d_in[3];
  const int*   emask = (const int*)  d_in[4];
  const float* W_enc = (const float*)d_in[5];
  const float* b_enc = (const float*)d_in[6];
  const float* W_red = (const float*)d_in[7];
  const float* b_red = (const float*)d_in[8];
  const float* W_ih  = (const float*)d_in[9];
  const float* W_hh  = (const float*)d_in[10];
  const float* b_ih  = (const float*)d_in[11];
  const float* b_hh  = (const float*)d_in[12];
  const float* W_cat = (const float*)d_in[13];
  const float* b_cat = (const float*)d_in[14];
  const float* W_log = (const float*)d_in[15];
  const float* b_log = (const float*)d_in[16];
  float* out = (float*)d_out;
  float* ws  = (float*)d_ws;

  float* mem   = ws + 0ull;          // 6,553,600
  float* Wg    = ws + 6553600ull;    // 2,097,152
  float* Wct   = ws + 8650752ull;    // 1,662,976 (dead after k_prep; reused below)
  float* Gemb  = ws + 10313728ull;   // 2,097,152
  float* bcomb = ws + 12410880ull;   // 2,048
  float* hbuf  = ws + 12412928ull;   // 16,384
  float* c0    = ws + 12429312ull;   // 16,384
  float* c1    = ws + 12445696ull;   // 16,384
  float* ctxb  = ws + 12462080ull;   // 16,384
  float* cov   = ws + 13527040ull;   // 12,800
  float* part  = ws + 13539840ull;   // 524,288 (8 slices)
  __hip_bfloat16* lib = (__hip_bfloat16*)(ws + 14590464ull);   // 524,288 bf16
  // licat + wcatb live in the DEAD Wct region (Wct unused after k_prep/k_gemb)
  short* licat = (short*)(ws + 8650752ull);    // 1,048,576 shorts
  short* wcatb = (short*)(ws + 9175040ull);    // 524,288 shorts (ends 9437184 < 10313728)
  __hip_bfloat16* wlb = (__hip_bfloat16*)(ws + 15245824ull);   // 16,384,000 bf16
  // hi/lo split scratch OVERLAPS wlb region tail? No: placed after, but wlb needs
  // 8,192,000 floats-worth; keep split scratch overlapping wlb exactly as before:
  short* ehi = (short*)(ws + 15245824ull);   // 6,553,600 shorts
  short* elo = ehi + 6553600;                // 6,553,600 shorts
  short* whi = ehi + 13107200;               // 262,144 shorts
  short* wlo = ehi + 13369344;               // 262,144 shorts
  // NOTE: k_prep writes wlb (offset 15245824) AND ehi/elo (same region)!
  // wlb occupies shorts [0, 8192000*2) of this region = floats 15245824..23437824.
  // ehi/elo occupy shorts [0, 13631488). CONFLICT if fused. -> give wlb its own space:
  // ws total unknown but prior rounds used up to ~23.4M floats; place wlb after split:
  __hip_bfloat16* wlb2 = (__hip_bfloat16*)(ws + 22076416ull);  // after wlo end (15245824+13631488/2=22061568) pad to 22076416

  k_init<<<64,256,0,stream>>>(inits, hbuf, c0, ctxb, cov);
  k_bcombo<<<8,256,0,stream>>>(W_ih, b_red, b_ih, b_hh, bcomb);
  k_wcombo<<<dim3(13,32),256,0,stream>>>(W_ih, W_red, Wct);
  k_gemb<<<dim3(32,16),256,0,stream>>>(trg, Wct, bcomb, Gemb);
  k_prep<<<31360,256,0,stream>>>(Wct, W_hh, Wg, enc, W_enc, ehi, elo, whi, wlo,
                                 W_log, wlb2, W_cat, wcatb);
  k_memories<<<dim3(100,4),256,0,stream>>>(ehi, elo, whi, wlo, b_enc, mem);

  for (int t=0;t<32;t++){
    const float* c_in = (t&1) ? c1 : c0;
    float* c_out      = (t&1) ? c0 : c1;
    k_gates<<<dim3(8,32),512,0,stream>>>(ctxb, hbuf, Wg, part);
    k_lstm_energy<<<256,512,0,stream>>>(part, Gemb, c_in, c_out, hbuf, licat,
                                        mem, emask, out, t);
    k_ctx<<<256,512,0,stream>>>(out, mem, ctxb, licat, cov, t);
  }

  k_logitin<<<dim3(8,4),256,0,stream>>>(licat, wcatb, b_cat, lib);
  k_logits<<<dim3(8,256),256,0,stream>>>(lib, wlb2, b_log, out);
  k_scatter<<<1024,512,0,stream>>>(ext, out);
}

// Round 15
// 945.972 us; speedup vs baseline: 1.0644x; 1.0644x over previous
//
#include <hip/hip_runtime.h>
#include <hip/hip_bf16.h>

#define INF_F 1000000000000.0f

typedef __attribute__((ext_vector_type(8))) short bfrag8;
typedef __attribute__((ext_vector_type(4))) float facc4;
typedef __attribute__((ext_vector_type(4))) short short4v;

__device__ __forceinline__ float sigf(float x){ return 1.0f/(1.0f + expf(-x)); }
__device__ __forceinline__ short f2bf(float f){
  __hip_bfloat16 h = __float2bfloat16(f);
  return *reinterpret_cast<short*>(&h);
}
__device__ __forceinline__ float bf2f(short s){
  unsigned u = ((unsigned)(unsigned short)s) << 16;
  return *reinterpret_cast<float*>(&u);
}

// out-region offsets (floats)
#define OFF_LOG 0ull
#define OFF_A   32819200ull
#define OFF_C   33228800ull
#define OFF_E   33638400ull

// ---------------- init ----------------
__global__ __launch_bounds__(256) void k_init(const float* __restrict__ init_s,
    float* __restrict__ hbuf, float* __restrict__ c0, float* __restrict__ ctxb,
    float* __restrict__ cov) {
  int i = blockIdx.x*256 + threadIdx.x;
  if (i < 32*512) { float v = init_s[i]; hbuf[i]=v; c0[i]=v; ctxb[i]=0.0f; }
  if (i < 32*400) cov[i] = 0.0f;
}

// ---------------- b_combo = W_ih@b_red + b_ih + b_hh ----------------
__global__ __launch_bounds__(256) void k_bcombo(const float* __restrict__ W_ih,
    const float* __restrict__ b_red, const float* __restrict__ b_ih,
    const float* __restrict__ b_hh, float* __restrict__ bcomb) {
  int j = blockIdx.x*256 + threadIdx.x;
  if (j >= 2048) return;
  float acc = b_ih[j] + b_hh[j];
  for (int m=0;m<300;m++) acc += W_ih[j*300+m]*b_red[m];
  bcomb[j] = acc;
}

// ---------------- Wct[2048][812] = W_ih[2048x300] @ W_red[300x812] ----------------
__global__ __launch_bounds__(256) void k_wcombo(const float* __restrict__ W_ih,
    const float* __restrict__ W_red, float* __restrict__ Wct) {
  __shared__ float As[16][68];
  __shared__ float Bs[16][68];
  int tid = threadIdx.x;
  int m0 = blockIdx.y*64, n0 = blockIdx.x*64;
  int rl = tid>>2, kq = (tid&3)*4;
  int kl = tid>>4, c4 = (tid&15)*4;
  int tx = tid&15, ty = tid>>4;
  float acc[4][4]={};
  for (int kk=0;kk<300;kk+=16){
    #pragma unroll
    for (int q=0;q<4;q++){
      int kg = kk+kq+q;
      As[kq+q][rl] = (kg<300) ? W_ih[(size_t)(m0+rl)*300 + kg] : 0.0f;
    }
    #pragma unroll
    for (int q=0;q<4;q++){
      int c = n0 + c4 + q;
      Bs[kl][c4+q] = (kk+kl<300 && c<812) ? W_red[(size_t)(kk+kl)*812 + c] : 0.0f;
    }
    __syncthreads();
    #pragma unroll
    for (int k=0;k<16;k++){
      const float* ap=&As[k][ty*4]; const float* bp=&Bs[k][tx*4];
      #pragma unroll
      for (int i=0;i<4;i++)
        #pragma unroll
        for (int j=0;j<4;j++) acc[i][j] += ap[i]*bp[j];
    }
    __syncthreads();
  }
  #pragma unroll
  for (int i=0;i<4;i++)
    #pragma unroll
    for (int j=0;j<4;j++){
      int row = m0+ty*4+i, col = n0+tx*4+j;
      if (col<812) Wct[(size_t)row*812 + col] = acc[i][j];
    }
}

// ---------------- G_emb[1024][2048] = emb[1024x300] @ Wct[:,0:300]^T + b_combo --------
__global__ __launch_bounds__(256) void k_gemb(const float* __restrict__ trg,
    const float* __restrict__ Wct, const float* __restrict__ bcomb,
    float* __restrict__ Gemb) {
  __shared__ float As[16][68];
  __shared__ float Bs[16][68];
  int tid = threadIdx.x;
  int m0 = blockIdx.y*64, n0 = blockIdx.x*64;
  int rl = tid>>2, kq = (tid&3)*4;
  int tx = tid&15, ty = tid>>4;
  float acc[4][4]={};
  int r = m0 + rl;
  const float* arow = trg + (size_t)(r&31)*9600 + (size_t)(r>>5)*300;
  for (int kk=0;kk<300;kk+=16){
    #pragma unroll
    for (int q=0;q<4;q++){
      int kg = kk+kq+q;
      As[kq+q][rl] = (kg<300) ? arow[kg] : 0.0f;
      Bs[kq+q][rl] = (kg<300) ? Wct[(size_t)(n0+rl)*812 + kg] : 0.0f;
    }
    __syncthreads();
    #pragma unroll
    for (int k=0;k<16;k++){
      const float* ap=&As[k][ty*4]; const float* bp=&Bs[k][tx*4];
      #pragma unroll
      for (int i=0;i<4;i++)
        #pragma unroll
        for (int j=0;j<4;j++) acc[i][j] += ap[i]*bp[j];
    }
    __syncthreads();
  }
  #pragma unroll
  for (int i=0;i<4;i++)
    #pragma unroll
    for (int j=0;j<4;j++){
      int rr = m0+ty*4+i, col = n0+tx*4+j;
      Gemb[(size_t)rr*2048 + col] = acc[i][j] + bcomb[col];
    }
}

// ---------------- fused prep: Wg pack + enc/W_enc hi-lo split + W_log/W_cat conv -----
__global__ __launch_bounds__(256) void k_prep(const float* __restrict__ Wct,
    const float* __restrict__ W_hh, float* __restrict__ Wg,
    const float* __restrict__ enc, const float* __restrict__ W_enc,
    short* __restrict__ ehi, short* __restrict__ elo,
    short* __restrict__ whi, short* __restrict__ wlo,
    const float* __restrict__ W_log, __hip_bfloat16* __restrict__ wlb,
    const float* __restrict__ W_cat, short* __restrict__ wcatb) {
  int bx = blockIdx.x;
  if (bx < 8192) {
    int idx = bx*256 + threadIdx.x;
    int k = idx >> 11, j = idx & 2047;
    Wg[idx] = (k < 512) ? Wct[(size_t)j*812 + 300 + k] : W_hh[(size_t)j*512 + (k-512)];
  } else if (bx < 14848) {
    int i4 = (bx-8192)*256 + threadIdx.x;
    const float* src; short* dhi; short* dlo; size_t off;
    if (i4 < 1638400) { src = enc;   dhi = ehi; dlo = elo; off = (size_t)i4*4; }
    else { int j4 = i4 - 1638400; if (j4 >= 65536) return;
           src = W_enc; dhi = whi; dlo = wlo; off = (size_t)j4*4; }
    float4 v = *(const float4*)(src + off);
    float f[4] = {v.x, v.y, v.z, v.w};
    short4v h, l;
    #pragma unroll
    for (int q=0;q<4;q++){
      short hb = f2bf(f[q]);
      float rr = f[q] - bf2f(hb);
      h[q] = hb; l[q] = f2bf(rr);
    }
    *(short4v*)(dhi + off) = h;
    *(short4v*)(dlo + off) = l;
  } else {
    int i4 = (bx-14848)*256 + threadIdx.x;
    if (i4 < 4096000) {
      const float4 v = *(const float4*)(W_log + (size_t)i4*4);
      size_t o = (size_t)i4*4;
      wlb[o+0] = __float2bfloat16(v.x); wlb[o+1] = __float2bfloat16(v.y);
      wlb[o+2] = __float2bfloat16(v.z); wlb[o+3] = __float2bfloat16(v.w);
    } else {
      int j4 = i4 - 4096000;
      if (j4 >= 131072) return;
      const float4 v = *(const float4*)(W_cat + (size_t)j4*4);
      short4v s;
      s[0]=f2bf(v.x); s[1]=f2bf(v.y); s[2]=f2bf(v.z); s[3]=f2bf(v.w);
      *(short4v*)(wcatb + (size_t)j4*4) = s;
    }
  }
}

// swizzled LDS byte offset: row in [0,128), slot in [0,4) (16B granules of a 64B row)
__device__ __forceinline__ int lds_off(int row, int slot) {
  return (row<<6) + (((slot ^ ((row>>1)&3))&3)<<4);
}

// ---------------- memories = enc @ W_enc^T + b_enc  (split-precision 3xbf16 MFMA) ----
__global__ __launch_bounds__(256) void k_memories(const short* __restrict__ Ahg,
    const short* __restrict__ Alg, const short* __restrict__ Bhg,
    const short* __restrict__ Blg, const float* __restrict__ bias,
    float* __restrict__ mem) {
  __shared__ short Ah[4096];
  __shared__ short Al[4096];
  __shared__ short Bh[4096];
  __shared__ short Bl[4096];
  int tid = threadIdx.x;
  int m0 = blockIdx.x*128, n0 = blockIdx.y*128;
  int w = tid>>6, lane = tid&63;
  int wr = w>>1, wc = w&1;
  int lr = lane&15, kg2 = lane>>4;

  int srow = tid>>1;
  int ss   = (tid&1)*2;
  const short* gah = Ahg + (size_t)(m0+srow)*512 + ss*8;
  const short* gal = Alg + (size_t)(m0+srow)*512 + ss*8;
  const short* gbh = Bhg + (size_t)(n0+srow)*512 + ss*8;
  const short* gbl = Blg + (size_t)(n0+srow)*512 + ss*8;
  int wo0 = lds_off(srow, ss), wo1 = lds_off(srow, ss+1);

  int raoff[4], rboff[4];
  #pragma unroll
  for (int q=0;q<4;q++){
    raoff[q] = lds_off(wr*64 + q*16 + lr, kg2);
    rboff[q] = lds_off(wc*64 + q*16 + lr, kg2);
  }

  facc4 acc[4][4] = {};
  bfrag8 rah0 = *(const bfrag8*)(gah);
  bfrag8 rah1 = *(const bfrag8*)(gah+8);
  bfrag8 ral0 = *(const bfrag8*)(gal);
  bfrag8 ral1 = *(const bfrag8*)(gal+8);
  bfrag8 rbh0 = *(const bfrag8*)(gbh);
  bfrag8 rbh1 = *(const bfrag8*)(gbh+8);
  bfrag8 rbl0 = *(const bfrag8*)(gbl);
  bfrag8 rbl1 = *(const bfrag8*)(gbl+8);

  for (int i=0;i<16;i++){
    __syncthreads();
    *(bfrag8*)((char*)Ah + wo0) = rah0;
    *(bfrag8*)((char*)Ah + wo1) = rah1;
    *(bfrag8*)((char*)Al + wo0) = ral0;
    *(bfrag8*)((char*)Al + wo1) = ral1;
    *(bfrag8*)((char*)Bh + wo0) = rbh0;
    *(bfrag8*)((char*)Bh + wo1) = rbh1;
    *(bfrag8*)((char*)Bl + wo0) = rbl0;
    *(bfrag8*)((char*)Bl + wo1) = rbl1;
    __syncthreads();
    if (i<15){
      gah += 32; gal += 32; gbh += 32; gbl += 32;
      rah0 = *(const bfrag8*)(gah);
      rah1 = *(const bfrag8*)(gah+8);
      ral0 = *(const bfrag8*)(gal);
      ral1 = *(const bfrag8*)(gal+8);
      rbh0 = *(const bfrag8*)(gbh);
      rbh1 = *(const bfrag8*)(gbh+8);
      rbl0 = *(const bfrag8*)(gbl);
      rbl1 = *(const bfrag8*)(gbl+8);
    }
    bfrag8 afh[4], afl[4], bfh[4], bfl[4];
    #pragma unroll
    for (int q=0;q<4;q++){
      afh[q] = *(const bfrag8*)((char*)Ah + raoff[q]);
      afl[q] = *(const bfrag8*)((char*)Al + raoff[q]);
      bfh[q] = *(const bfrag8*)((char*)Bh + rboff[q]);
      bfl[q] = *(const bfrag8*)((char*)Bl + rboff[q]);
    }
    #pragma unroll
    for (int mi=0;mi<4;mi++)
      #pragma unroll
      for (int ni=0;ni<4;ni++){
        acc[mi][ni] = __builtin_amdgcn_mfma_f32_16x16x32_bf16(afl[mi], bfh[ni], acc[mi][ni], 0,0,0);
        acc[mi][ni] = __builtin_amdgcn_mfma_f32_16x16x32_bf16(afh[mi], bfl[ni], acc[mi][ni], 0,0,0);
        acc[mi][ni] = __builtin_amdgcn_mfma_f32_16x16x32_bf16(afh[mi], bfh[ni], acc[mi][ni], 0,0,0);
      }
  }

  #pragma unroll
  for (int mi=0;mi<4;mi++){
    int row = m0 + wr*64 + mi*16 + kg2*4;
    #pragma unroll
    for (int ni=0;ni<4;ni++){
      int col = n0 + wc*64 + ni*16 + lr;
      float bl = bias[col];
      #pragma unroll
      for (int q=0;q<4;q++)
        mem[(size_t)(row+q)*512 + col] = acc[mi][ni][q] + bl;
    }
  }
}

// ---------------- per-step: gates partial GEMM (16 k-slices of 64, 512 threads) ------
// grid (ks=16, rc=16); partial[ks*32+b][row] = sum_{k in slice} yh[b][k]*Wg[k][row]
__global__ __launch_bounds__(512) void k_gates(const float* __restrict__ ctxb,
    const float* __restrict__ hbuf, const float* __restrict__ Wg,
    float* __restrict__ partials) {
  __shared__ float yh_s[64][32];
  int ks = blockIdx.x;
  int rc = blockIdx.y;
  int tid = threadIdx.x;
  const float* side = (ks < 8) ? ctxb : hbuf;
  int kbase = (ks & 7) * 64;
  {
    int b_l = tid & 31, kq0 = (tid >> 5) * 4;
    const float* src = side + (size_t)b_l*512 + kbase + kq0;
    float4 v = *(const float4*)src;
    yh_s[kq0+0][b_l]=v.x; yh_s[kq0+1][b_l]=v.y;
    yh_s[kq0+2][b_l]=v.z; yh_s[kq0+3][b_l]=v.w;
  }
  __syncthreads();
  int tr = tid & 63, bg = tid >> 6;     // 64 row-pairs, 8 b-groups of 4
  int row0 = rc*128 + tr*2;
  float acc[2][4] = {};
  const float* wp = Wg + (size_t)(ks*64)*2048 + row0;
  #pragma unroll 8
  for (int k=0;k<64;k++){
    float2 w = *(const float2*)(wp + (size_t)k*2048);
    float4 y = *(const float4*)&yh_s[k][bg*4];
    acc[0][0]+=w.x*y.x; acc[0][1]+=w.x*y.y; acc[0][2]+=w.x*y.z; acc[0][3]+=w.x*y.w;
    acc[1][0]+=w.y*y.x; acc[1][1]+=w.y*y.y; acc[1][2]+=w.y*y.z; acc[1][3]+=w.y*y.w;
  }
  #pragma unroll
  for (int j=0;j<4;j++){
    float2 o; o.x=acc[0][j]; o.y=acc[1][j];
    *(float2*)(partials + (size_t)(ks*32 + bg*4 + j)*2048 + row0) = o;
  }
}

// ---------------- per-step: partial reduce (16) + LSTM + energy chunk (512 thr) ------
// grid 256 linear blocks: b = blk&31, sc = blk>>5
__global__ __launch_bounds__(512) void k_lstm_energy(const float* __restrict__ part,
    const float* __restrict__ Gemb,
    const float* __restrict__ c_in, float* __restrict__ c_out,
    float* __restrict__ hbuf, short* __restrict__ licat,
    const float* __restrict__ mem, const int* __restrict__ emask,
    float* __restrict__ out, int t) {
  __shared__ float hl[512];
  int blk = blockIdx.x, tid = threadIdx.x;
  int b = blk & 31, sc = blk >> 5;
  int r = t*32 + b;
  int lane = tid & 63, w = tid >> 6;   // 8 waves
  {
    int j = tid;
    const float* gp = Gemb + (size_t)r*2048;
    float g[4];
    #pragma unroll
    for (int gi=0; gi<4; gi++){
      int row = gi*512 + j;
      float v = gp[row];
      #pragma unroll
      for (int ks=0; ks<16; ks++)
        v += part[(size_t)(ks*32+b)*2048 + row];
      g[gi] = v;
    }
    float cp = c_in[b*512+j];
    float cn = sigf(g[1])*cp + sigf(g[0])*tanhf(g[2]);
    float hn = sigf(g[3])*tanhf(cn);
    hl[j] = hn;
    if (sc==0){
      c_out[b*512+j]=cn; hbuf[b*512+j]=hn;
      licat[(size_t)r*1024 + j] = f2bf(hn);
    }
  }
  __syncthreads();
  float4 h0 = *(const float4*)&hl[lane*8];
  float4 h1 = *(const float4*)&hl[lane*8+4];
  const float* mb = mem + (size_t)b*204800;
  const int* em = emask + b*400;
  for (int i=0;i<7;i++){
    int s_l = i*8 + w;
    if (s_l < 50){
      int s = sc*50 + s_l;
      const float4* mp = (const float4*)(mb + (size_t)s*512 + lane*8);
      float4 m0 = mp[0], m1 = mp[1];
      float acc = h0.x*m0.x + h0.y*m0.y + h0.z*m0.z + h0.w*m0.w
                + h1.x*m1.x + h1.y*m1.y + h1.z*m1.z + h1.w*m1.w;
      #pragma unroll
      for (int off=32; off; off>>=1) acc += __shfl_xor(acc, off);
      if (lane==0){
        out[OFF_E + (size_t)r*400 + s] = (em[s]==0) ? -INF_F : acc;
      }
    }
  }
}

// ---------------- per-step: softmax + ctx chunk (64 h, 8 s-eighths) + attn/cov -------
// grid 256 linear blocks: b = blk&31, hc = blk>>5 (8 chunks x 64 h), 512 threads
__global__ __launch_bounds__(512) void k_ctx(float* __restrict__ out,
    const float* __restrict__ mem, float* __restrict__ ctxb, short* __restrict__ licat,
    float* __restrict__ cov, int t) {
  __shared__ float ps[400];
  __shared__ float red[16];
  __shared__ float tmp[512];
  int blk = blockIdx.x, tid = threadIdx.x;
  int b = blk & 31, hc = blk >> 5;
  int r = t*32 + b;
  int lane = tid & 63, w = tid >> 6;   // 8 waves
  float e = (tid < 400) ? out[OFF_E + (size_t)r*400 + tid] : -3.4e38f;
  float lm = e;
  #pragma unroll
  for (int off=32; off; off>>=1) lm = fmaxf(lm, __shfl_xor(lm, off));
  if (lane==0) red[w] = lm;
  __syncthreads();
  float m = red[0];
  #pragma unroll
  for (int i=1;i<8;i++) m = fmaxf(m, red[i]);
  float pv = (tid < 400) ? expf(e - m) : 0.0f;
  float sv = pv;
  #pragma unroll
  for (int off=32; off; off>>=1) sv += __shfl_xor(sv, off);
  if (lane==0) red[8+w] = sv;
  __syncthreads();
  float sum = red[8];
  #pragma unroll
  for (int i=1;i<8;i++) sum += red[8+i];
  float inv = 1.0f/sum;
  if (tid < 400) ps[tid] = pv*inv;
  __syncthreads();
  // ctx chunk: 64 h, eight s-eighths of 50
  int hloc = tid & 63, sh = tid >> 6;
  int h = hc*64 + hloc;
  float acc = 0.0f;
  {
    const float* mqs = mem + (size_t)b*204800 + h + (size_t)sh*50*512;
    const float* pss = &ps[sh*50];
    #pragma unroll 10
    for (int s=0;s<50;s++) acc += pss[s]*mqs[(size_t)s*512];
  }
  tmp[sh*64 + hloc] = acc;
  __syncthreads();
  if (sh==0){
    float v = acc;
    #pragma unroll
    for (int q=1;q<8;q++) v += tmp[q*64 + hloc];
    ctxb[b*512+h] = v;
    licat[(size_t)r*1024 + 512 + h] = f2bf(v);
  }
  if (hc==0 && tid<400){
    float a = ps[tid];
    out[OFF_A + (size_t)r*400 + tid] = a;
    float cv = cov[b*400+tid];
    out[OFF_C + (size_t)r*400 + tid] = cv;
    cov[b*400+tid] = cv + a;
  }
}

// ---------------- logit_in = tanh(licat @ wcatb^T + b_cat) -> bf16 (MFMA, prefetch) --
__global__ __launch_bounds__(256) void k_logitin(const short* __restrict__ Ab,
    const short* __restrict__ Wb, const float* __restrict__ b_cat,
    __hip_bfloat16* __restrict__ lib) {
  __shared__ short As[4096];
  __shared__ short Bs[4096];
  int tid = threadIdx.x;
  int m0 = blockIdx.x*128, n0 = blockIdx.y*128;
  int w = tid>>6, lane = tid&63;
  int wr = w>>1, wc = w&1;
  int lr = lane&15, kg2 = lane>>4;

  int srow = tid>>1;
  int ss   = (tid&1)*2;
  const short* ga = Ab + (size_t)(m0+srow)*1024 + ss*8;
  const short* gw = Wb + (size_t)(n0+srow)*1024 + ss*8;
  int wo0 = lds_off(srow, ss), wo1 = lds_off(srow, ss+1);

  int raoff[4], rboff[4];
  #pragma unroll
  for (int q=0;q<4;q++){
    raoff[q] = lds_off(wr*64 + q*16 + lr, kg2);
    rboff[q] = lds_off(wc*64 + q*16 + lr, kg2);
  }

  facc4 acc[4][4] = {};
  bfrag8 ra0 = *(const bfrag8*)(ga);
  bfrag8 ra1 = *(const bfrag8*)(ga+8);
  bfrag8 rb0 = *(const bfrag8*)(gw);
  bfrag8 rb1 = *(const bfrag8*)(gw+8);

  for (int i=0;i<32;i++){
    __syncthreads();
    *(bfrag8*)((char*)As + wo0) = ra0;
    *(bfrag8*)((char*)As + wo1) = ra1;
    *(bfrag8*)((char*)Bs + wo0) = rb0;
    *(bfrag8*)((char*)Bs + wo1) = rb1;
    __syncthreads();
    if (i<31){
      ga += 32; gw += 32;
      ra0 = *(const bfrag8*)(ga);
      ra1 = *(const bfrag8*)(ga+8);
      rb0 = *(const bfrag8*)(gw);
      rb1 = *(const bfrag8*)(gw+8);
    }
    bfrag8 af[4], bf[4];
    #pragma unroll
    for (int q=0;q<4;q++){
      af[q] = *(const bfrag8*)((char*)As + raoff[q]);
      bf[q] = *(const bfrag8*)((char*)Bs + rboff[q]);
    }
    #pragma unroll
    for (int mi=0;mi<4;mi++)
      #pragma unroll
      for (int ni=0;ni<4;ni++)
        acc[mi][ni] = __builtin_amdgcn_mfma_f32_16x16x32_bf16(af[mi], bf[ni], acc[mi][ni], 0,0,0);
  }

  #pragma unroll
  for (int mi=0;mi<4;mi++){
    int row = m0 + wr*64 + mi*16 + kg2*4;
    #pragma unroll
    for (int ni=0;ni<4;ni++){
      int col = n0 + wc*64 + ni*16 + lr;
      float bc = b_cat[col];
      #pragma unroll
      for (int q=0;q<4;q++){
        float v = tanhf(acc[mi][ni][q] + bc);
        lib[(size_t)(row+q)*512 + col] = __float2bfloat16(v);
      }
    }
  }
}

// ---------------- logits = logit_in @ W_log^T + b_log (bf16 MFMA, XCD swizzle) ------
__global__ __launch_bounds__(256) void k_logits(const __hip_bfloat16* __restrict__ Ab,
    const __hip_bfloat16* __restrict__ Wb, const float* __restrict__ b_log,
    float* __restrict__ out) {
  __shared__ short As[4096];
  __shared__ short Bs[4096];
  int m = blockIdx.y & 7;
  int yy = blockIdx.x + 8*(blockIdx.y >> 3);
  if (yy >= 250) return;
  int tid = threadIdx.x;
  int m0 = m*128, n0 = yy*128;
  int w = tid>>6, lane = tid&63;
  int wr = w>>1, wc = w&1;
  int lr = lane&15, kg2 = lane>>4;
  const short* A = (const short*)Ab;
  const short* W = (const short*)Wb;

  int srow = tid>>1;
  int ss   = (tid&1)*2;
  const short* ga = A + (size_t)(m0+srow)*512 + ss*8;
  const short* gw = W + (size_t)(n0+srow)*512 + ss*8;
  int wo0 = lds_off(srow, ss), wo1 = lds_off(srow, ss+1);

  int raoff[4], rboff[4];
  #pragma unroll
  for (int q=0;q<4;q++){
    raoff[q] = lds_off(wr*64 + q*16 + lr, kg2);
    rboff[q] = lds_off(wc*64 + q*16 + lr, kg2);
  }

  facc4 acc[4][4] = {};
  bfrag8 ra0 = *(const bfrag8*)(ga);
  bfrag8 ra1 = *(const bfrag8*)(ga+8);
  bfrag8 rb0 = *(const bfrag8*)(gw);
  bfrag8 rb1 = *(const bfrag8*)(gw+8);

  for (int i=0;i<16;i++){
    __syncthreads();
    *(bfrag8*)((char*)As + wo0) = ra0;
    *(bfrag8*)((char*)As + wo1) = ra1;
    *(bfrag8*)((char*)Bs + wo0) = rb0;
    *(bfrag8*)((char*)Bs + wo1) = rb1;
    __syncthreads();
    if (i<15){
      ga += 32; gw += 32;
      ra0 = *(const bfrag8*)(ga);
      ra1 = *(const bfrag8*)(ga+8);
      rb0 = *(const bfrag8*)(gw);
      rb1 = *(const bfrag8*)(gw+8);
    }
    bfrag8 af[4], bf[4];
    #pragma unroll
    for (int q=0;q<4;q++){
      af[q] = *(const bfrag8*)((char*)As + raoff[q]);
      bf[q] = *(const bfrag8*)((char*)Bs + rboff[q]);
    }
    #pragma unroll
    for (int mi=0;mi<4;mi++)
      #pragma unroll
      for (int ni=0;ni<4;ni++)
        acc[mi][ni] = __builtin_amdgcn_mfma_f32_16x16x32_bf16(af[mi], bf[ni], acc[mi][ni], 0,0,0);
  }

  #pragma unroll
  for (int mi=0;mi<4;mi++){
    int row = m0 + wr*64 + mi*16 + kg2*4;
    #pragma unroll
    for (int ni=0;ni<4;ni++){
      int col = n0 + wc*64 + ni*16 + lr;
      float bl = b_log[col];
      #pragma unroll
      for (int q=0;q<4;q++){
        float v = acc[mi][ni][q] + bl;
        out[(size_t)(row+q)*32050 + col] = (v == 0.0f) ? -INF_F : v;
      }
    }
  }
}

// ---------------- scatter-max of energies into extended logits (+ OOV fill) ---------
__global__ __launch_bounds__(512) void k_scatter(const int* __restrict__ ext_src,
    float* __restrict__ out) {
  __shared__ int tok[400];
  __shared__ float ev[400];
  int rr = blockIdx.x;
  int b = rr & 31;
  int tid = threadIdx.x;
  if (tid >= 400 && tid < 450)
    out[(size_t)rr*32050 + 32000 + (tid-400)] = -INF_F;
  if (tid < 400){
    tok[tid] = ext_src[b*400+tid];
    ev[tid]  = out[OFF_E + (size_t)rr*400 + tid];
  }
  __syncthreads();
  if (tid < 400){
    int tk = tok[tid];
    float m = -3.4e38f;
    bool pre = false;
    #pragma unroll 1
    for (int s2=0; s2<400; s2+=8){
      #pragma unroll
      for (int q=0;q<8;q++){
        int tk2 = tok[s2+q];
        float e2 = ev[s2+q];
        bool eq = (tk2==tk);
        m = fmaxf(m, eq ? e2 : -3.4e38f);
        pre = pre || (eq && (s2+q) < tid);
      }
    }
    if (!pre && m != -INF_F){
      size_t idx = (size_t)rr*32050 + tk;
      float wv = out[idx];
      float extv = (wv == -INF_F) ? 0.0f : wv;
      float nv = extv + m;
      out[idx] = (nv == 0.0f) ? -INF_F : nv;
    }
  }
}

extern "C" void kernel_launch(void* const* d_in, const int* in_sizes, int n_in,
                              void* d_out, int out_size, void* d_ws, size_t ws_size,
                              hipStream_t stream) {
  const float* trg   = (const float*)d_in[0];
  const int*   ext   = (const int*)  d_in[1];
  const float* inits = (const float*)d_in[2];
  const float* enc   = (const float*)d_in[3];
  const int*   emask = (const int*)  d_in[4];
  const float* W_enc = (const float*)d_in[5];
  const float* b_enc = (const float*)d_in[6];
  const float* W_red = (const float*)d_in[7];
  const float* b_red = (const float*)d_in[8];
  const float* W_ih  = (const float*)d_in[9];
  const float* W_hh  = (const float*)d_in[10];
  const float* b_ih  = (const float*)d_in[11];
  const float* b_hh  = (const float*)d_in[12];
  const float* W_cat = (const float*)d_in[13];
  const float* b_cat = (const float*)d_in[14];
  const float* W_log = (const float*)d_in[15];
  const float* b_log = (const float*)d_in[16];
  float* out = (float*)d_out;
  float* ws  = (float*)d_ws;

  float* mem   = ws + 0ull;          // 6,553,600
  float* Wg    = ws + 6553600ull;    // 2,097,152
  float* Wct   = ws + 8650752ull;    // 1,662,976 (dead after k_prep; reused below)
  float* Gemb  = ws + 10313728ull;   // 2,097,152
  float* bcomb = ws + 12410880ull;   // 2,048
  float* hbuf  = ws + 12412928ull;   // 16,384
  float* c0    = ws + 12429312ull;   // 16,384
  float* c1    = ws + 12445696ull;   // 16,384
  float* ctxb  = ws + 12462080ull;   // 16,384
  float* cov   = ws + 13527040ull;   // 12,800
  float* part  = ws + 13539840ull;   // 1,048,576 (16 slices; ends 14588416 < 14590464)
  __hip_bfloat16* lib = (__hip_bfloat16*)(ws + 14590464ull);   // 524,288 bf16
  // licat + wcatb live in the DEAD Wct region (Wct unused after k_prep/k_gemb)
  short* licat = (short*)(ws + 8650752ull);    // 1,048,576 shorts
  short* wcatb = (short*)(ws + 9175040ull);    // 524,288 shorts (ends 9437184 < 10313728)
  // hi/lo split scratch
  short* ehi = (short*)(ws + 15245824ull);   // 6,553,600 shorts
  short* elo = ehi + 6553600;                // 6,553,600 shorts
  short* whi = ehi + 13107200;               // 262,144 shorts
  short* wlo = ehi + 13369344;               // 262,144 shorts
  // wlb gets its OWN region after the split scratch (k_prep writes both)
  __hip_bfloat16* wlb2 = (__hip_bfloat16*)(ws + 22076416ull);

  k_init<<<64,256,0,stream>>>(inits, hbuf, c0, ctxb, cov);
  k_bcombo<<<8,256,0,stream>>>(W_ih, b_red, b_ih, b_hh, bcomb);
  k_wcombo<<<dim3(13,32),256,0,stream>>>(W_ih, W_red, Wct);
  k_gemb<<<dim3(32,16),256,0,stream>>>(trg, Wct, bcomb, Gemb);
  k_prep<<<31360,256,0,stream>>>(Wct, W_hh, Wg, enc, W_enc, ehi, elo, whi, wlo,
                                 W_log, wlb2, W_cat, wcatb);
  k_memories<<<dim3(100,4),256,0,stream>>>(ehi, elo, whi, wlo, b_enc, mem);

  for (int t=0;t<32;t++){
    const float* c_in = (t&1) ? c1 : c0;
    float* c_out      = (t&1) ? c0 : c1;
    k_gates<<<dim3(16,16),512,0,stream>>>(ctxb, hbuf, Wg, part);
    k_lstm_energy<<<256,512,0,stream>>>(part, Gemb, c_in, c_out, hbuf, licat,
                                        mem, emask, out, t);
    k_ctx<<<256,512,0,stream>>>(out, mem, ctxb, licat, cov, t);
  }

  k_logitin<<<dim3(8,4),256,0,stream>>>(licat, wcatb, b_cat, lib);
  k_logits<<<dim3(8,256),256,0,stream>>>(lib, wlb2, b_log, out);
  k_scatter<<<1024,512,0,stream>>>(ext, out);
}